// Round 1
// 12759.734 us; speedup vs baseline: 1.9622x; 1.9622x over previous
//
#include <hip/hip_runtime.h>
#include <hip/hip_bf16.h>
#include <math.h>

// Problem constants (GPT-2 small, B=2, S=1024)
#define VOCAB 50257
#define DMODEL 768
#define NHEAD 12
#define NPOS 1024
#define NLAYER 12
#define BATCH 2
#define SEQ 1024
#define HEADD 64
#define DFF 3072
#define MROWS (BATCH * SEQ)   // 2048

// ---------------------------------------------------------------------------
// pos_ids: cumsum(mask)-1, pinned to 0 where mask==0
// ---------------------------------------------------------------------------
__global__ void pos_ids_kernel(const float* __restrict__ mask, int* __restrict__ pos_ids) {
    int tid = blockIdx.x * blockDim.x + threadIdx.x;
    if (tid >= BATCH * SEQ) return;
    int b = tid / SEQ;
    int s = tid % SEQ;
    float am = mask[tid];
    if (am == 0.0f) { pos_ids[tid] = 0; return; }
    float acc = 0.0f;
    const float* row = mask + b * SEQ;
    for (int t = 0; t <= s; ++t) acc += row[t];
    pos_ids[tid] = (int)(acc - 1.0f);
}

// ---------------------------------------------------------------------------
// embedding: x[bs, d] = tok_emb[ids[bs]][d] + pos_emb[pos_ids[bs]][d]
// ---------------------------------------------------------------------------
__global__ void embed_kernel(const int* __restrict__ ids, const int* __restrict__ pos_ids,
                             const float* __restrict__ tok_emb, const float* __restrict__ pos_emb,
                             float* __restrict__ x) {
    int idx = blockIdx.x * blockDim.x + threadIdx.x;
    if (idx >= MROWS * DMODEL) return;
    int bs = idx / DMODEL;
    int d  = idx % DMODEL;
    int id = ids[bs];
    int p  = pos_ids[bs];
    x[idx] = tok_emb[(size_t)id * DMODEL + d] + pos_emb[(size_t)p * DMODEL + d];
}

// ---------------------------------------------------------------------------
// LayerNorm: one block (256 threads) per row of 768
// ---------------------------------------------------------------------------
__device__ inline float wave_sum64(float v) {
    #pragma unroll
    for (int off = 32; off >= 1; off >>= 1) v += __shfl_xor(v, off, 64);
    return v;
}

__global__ __launch_bounds__(256) void layernorm_kernel(
    const float* __restrict__ x, const float* __restrict__ g, const float* __restrict__ b,
    float* __restrict__ out) {
    int row = blockIdx.x;
    int tid = threadIdx.x;
    const float* xr = x + (size_t)row * DMODEL;
    float v0 = xr[tid], v1 = xr[tid + 256], v2 = xr[tid + 512];

    __shared__ float red[4];
    int wave = tid >> 6, lane = tid & 63;

    float s = wave_sum64(v0 + v1 + v2);
    if (lane == 0) red[wave] = s;
    __syncthreads();
    float mean = (red[0] + red[1] + red[2] + red[3]) * (1.0f / DMODEL);
    __syncthreads();

    float d0 = v0 - mean, d1 = v1 - mean, d2 = v2 - mean;
    float s2 = wave_sum64(d0 * d0 + d1 * d1 + d2 * d2);
    if (lane == 0) red[wave] = s2;
    __syncthreads();
    float var = (red[0] + red[1] + red[2] + red[3]) * (1.0f / DMODEL);
    float inv = 1.0f / sqrtf(var + 1e-5f);

    float* outr = out + (size_t)row * DMODEL;
    outr[tid]       = d0 * inv * g[tid]       + b[tid];
    outr[tid + 256] = d1 * inv * g[tid + 256] + b[tid + 256];
    outr[tid + 512] = d2 * inv * g[tid + 512] + b[tid + 512];
}

// ---------------------------------------------------------------------------
// GEMM: C[M,N] = A[M,K] @ B  (+bias)(+GELU)(+Res)
//   TRANSB=0: B is (K,N) row-major.  TRANSB=1: B is (N,K) row-major.
// 64x64 tile, BK=16, 256 threads, 4x4 microtile. M%64==0, K%16==0 assumed.
// ---------------------------------------------------------------------------
#define BM 64
#define BN 64
#define BKT 16

template<int TRANSB, int GELU>
__global__ __launch_bounds__(256) void gemm_kernel(
    const float* __restrict__ A, const float* __restrict__ B,
    const float* __restrict__ bias, const float* __restrict__ Res,
    float* __restrict__ C, int M, int N, int K) {
    __shared__ __align__(16) float As[BKT][BM];
    __shared__ __align__(16) float Bs[BKT][BN];

    int tid = threadIdx.x;
    int tx = tid & 15, ty = tid >> 4;
    int m0 = blockIdx.y * BM, n0 = blockIdx.x * BN;

    float acc[4][4] = {};

    // A-tile load mapping: 64 rows x 16 k, float4 per thread
    int arow = tid >> 2;           // 0..63
    int akq  = (tid & 3) << 2;     // 0,4,8,12
    // B-tile (nn): 16 k-rows x 64 cols
    int bkrow = tid >> 4;          // 0..15
    int bcol  = (tid & 15) << 2;   // 0..60
    // B-tile (nt): 64 n-rows x 16 k
    int bn  = tid >> 2;            // 0..63
    int bkq = (tid & 3) << 2;

    for (int k0 = 0; k0 < K; k0 += BKT) {
        float4 av = *(const float4*)(A + (size_t)(m0 + arow) * K + k0 + akq);
        As[akq + 0][arow] = av.x; As[akq + 1][arow] = av.y;
        As[akq + 2][arow] = av.z; As[akq + 3][arow] = av.w;

        if (TRANSB) {
            float4 bv = make_float4(0.f, 0.f, 0.f, 0.f);
            if (n0 + bn < N)
                bv = *(const float4*)(B + (size_t)(n0 + bn) * K + k0 + bkq);
            Bs[bkq + 0][bn] = bv.x; Bs[bkq + 1][bn] = bv.y;
            Bs[bkq + 2][bn] = bv.z; Bs[bkq + 3][bn] = bv.w;
        } else {
            if (n0 + bcol + 3 < N) {
                *(float4*)&Bs[bkrow][bcol] =
                    *(const float4*)(B + (size_t)(k0 + bkrow) * N + n0 + bcol);
            } else {
                #pragma unroll
                for (int j = 0; j < 4; ++j)
                    Bs[bkrow][bcol + j] =
                        (n0 + bcol + j < N) ? B[(size_t)(k0 + bkrow) * N + n0 + bcol + j] : 0.f;
            }
        }
        __syncthreads();

        #pragma unroll
        for (int kk = 0; kk < BKT; ++kk) {
            float4 a4 = *(const float4*)&As[kk][ty << 2];
            float4 b4 = *(const float4*)&Bs[kk][tx << 2];
            float avr[4] = {a4.x, a4.y, a4.z, a4.w};
            float bvr[4] = {b4.x, b4.y, b4.z, b4.w};
            #pragma unroll
            for (int i = 0; i < 4; ++i)
                #pragma unroll
                for (int j = 0; j < 4; ++j)
                    acc[i][j] += avr[i] * bvr[j];
        }
        __syncthreads();
    }

    #pragma unroll
    for (int i = 0; i < 4; ++i) {
        int m = m0 + (ty << 2) + i;
        #pragma unroll
        for (int j = 0; j < 4; ++j) {
            int n = n0 + (tx << 2) + j;
            if (n < N) {
                float v = acc[i][j];
                if (bias) v += bias[n];
                if (GELU) v = v * 0.5f * (1.0f + erff(v * 0.70710678118654752f));
                if (Res)  v += Res[(size_t)m * N + n];
                C[(size_t)m * N + n] = v;
            }
        }
    }
}

// ---------------------------------------------------------------------------
// Flash attention, tiled. One 256-thread block per (b, h, 64-row q-tile).
// K/V tiles (64 rows x 64 head-dims) staged in LDS with an XOR swizzle on the
// float4 column index (unswizzled [64][64] f32 column-slice reads are a
// 16-way bank conflict). P-tile reuses K's LDS buffer -> 48KB, 3 blocks/CU.
// Thread (tx,ty) owns rows ty*4+i, cols/dims tx*4+j. Online softmax state
// (m,l) replicated across the 16 tx lanes of a row via width-16 shfl reduce.
// ---------------------------------------------------------------------------
__global__ __launch_bounds__(256) void flash_attn_kernel(
    const float* __restrict__ q, const float* __restrict__ k, const float* __restrict__ v,
    const float* __restrict__ amask, float* __restrict__ out) {
    __shared__ __align__(16) float Qs[64 * 64];
    __shared__ __align__(16) float Ks[64 * 64];   // reused as P after S-compute
    __shared__ __align__(16) float Vs[64 * 64];

    const int nqt = SEQ / 64;
    int qt = blockIdx.x % nqt;
    int h  = (blockIdx.x / nqt) % NHEAD;
    int b  = blockIdx.x / (nqt * NHEAD);
    int q0 = qt * 64;

    int tid = threadIdx.x;
    int tx = tid & 15, ty = tid >> 4;

    const float* qbase = q + (size_t)(b * SEQ + q0) * DMODEL + h * HEADD;
    const float* kbase = k + (size_t)(b * SEQ) * DMODEL + h * HEADD;
    const float* vbase = v + (size_t)(b * SEQ) * DMODEL + h * HEADD;
    const float* mrow  = amask + (size_t)b * SEQ;

    // stage Q (pre-scaled by 1/sqrt(64))
    #pragma unroll
    for (int i = 0; i < 4; ++i) {
        int idx = tid + i * 256;
        int r = idx >> 4, c4 = idx & 15;
        float4 val = *(const float4*)(qbase + (size_t)r * DMODEL + (c4 << 2));
        val.x *= 0.125f; val.y *= 0.125f; val.z *= 0.125f; val.w *= 0.125f;
        int s4 = c4 ^ ((r >> 2) & 7);
        *(float4*)&Qs[r * 64 + (s4 << 2)] = val;
    }

    float m[4], l[4], o[4][4];
    #pragma unroll
    for (int i = 0; i < 4; ++i) {
        m[i] = -3.402823466e38f; l[i] = 0.0f;
        #pragma unroll
        for (int j = 0; j < 4; ++j) o[i][j] = 0.0f;
    }

    for (int j0 = 0; j0 <= q0; j0 += 64) {
        // stage K, V tiles (coalesced: 16 lanes x 16B = 256B per row)
        #pragma unroll
        for (int i = 0; i < 4; ++i) {
            int idx = tid + i * 256;
            int r = idx >> 4, c4 = idx & 15;
            int s4 = c4 ^ ((r >> 2) & 7);
            *(float4*)&Ks[r * 64 + (s4 << 2)] =
                *(const float4*)(kbase + (size_t)(j0 + r) * DMODEL + (c4 << 2));
            *(float4*)&Vs[r * 64 + (s4 << 2)] =
                *(const float4*)(vbase + (size_t)(j0 + r) * DMODEL + (c4 << 2));
        }
        __syncthreads();

        // S = (Q*scale) @ K^T for my 4x4 sub-block
        float s[4][4] = {};
        #pragma unroll
        for (int d4 = 0; d4 < 16; ++d4) {
            float4 qv[4], kv[4];
            #pragma unroll
            for (int i = 0; i < 4; ++i) {
                int r = ty * 4 + i;             // (r>>2)&7 == ty&7
                qv[i] = *(const float4*)&Qs[r * 64 + ((d4 ^ (ty & 7)) << 2)];
            }
            #pragma unroll
            for (int j = 0; j < 4; ++j) {
                int r = tx * 4 + j;             // (r>>2)&7 == tx&7
                kv[j] = *(const float4*)&Ks[r * 64 + ((d4 ^ (tx & 7)) << 2)];
            }
            #pragma unroll
            for (int i = 0; i < 4; ++i)
                #pragma unroll
                for (int j = 0; j < 4; ++j)
                    s[i][j] += qv[i].x * kv[j].x + qv[i].y * kv[j].y
                             + qv[i].z * kv[j].z + qv[i].w * kv[j].w;
        }

        // mask: causal + key-dim attention mask (finfo(f32).min like reference)
        #pragma unroll
        for (int j = 0; j < 4; ++j) {
            int kc = j0 + tx * 4 + j;
            float am = mrow[kc];
            #pragma unroll
            for (int i = 0; i < 4; ++i) {
                int qr = q0 + ty * 4 + i;
                if (kc > qr || am == 0.0f) s[i][j] = -3.402823466e38f;
            }
        }

        // online softmax (per-row state, replicated across the 16 tx lanes)
        float p[4][4];
        #pragma unroll
        for (int i = 0; i < 4; ++i) {
            float mx = fmaxf(fmaxf(s[i][0], s[i][1]), fmaxf(s[i][2], s[i][3]));
            #pragma unroll
            for (int off = 1; off < 16; off <<= 1) mx = fmaxf(mx, __shfl_xor(mx, off, 16));
            float mn = fmaxf(m[i], mx);
            float alpha = expf(m[i] - mn);
            float sum = 0.0f;
            #pragma unroll
            for (int j = 0; j < 4; ++j) { p[i][j] = expf(s[i][j] - mn); sum += p[i][j]; }
            #pragma unroll
            for (int off = 1; off < 16; off <<= 1) sum += __shfl_xor(sum, off, 16);
            l[i] = l[i] * alpha + sum;
            m[i] = mn;
            #pragma unroll
            for (int j = 0; j < 4; ++j) o[i][j] *= alpha;
        }

        __syncthreads();   // all waves done reading Ks -> safe to overwrite with P

        #pragma unroll
        for (int i = 0; i < 4; ++i) {
            int r = ty * 4 + i;
            float4 pv = make_float4(p[i][0], p[i][1], p[i][2], p[i][3]);
            *(float4*)&Ks[r * 64 + ((tx ^ (ty & 7)) << 2)] = pv;   // c4 = tx
        }
        __syncthreads();

        // O += P @ V : o[i][j] += sum_k P[ty*4+i][k] * V[k][tx*4+j]
        #pragma unroll
        for (int k4 = 0; k4 < 16; ++k4) {
            float pa[4][4];
            #pragma unroll
            for (int i = 0; i < 4; ++i) {
                int r = ty * 4 + i;
                float4 t = *(const float4*)&Ks[r * 64 + ((k4 ^ (ty & 7)) << 2)];
                pa[i][0] = t.x; pa[i][1] = t.y; pa[i][2] = t.z; pa[i][3] = t.w;
            }
            #pragma unroll
            for (int kk = 0; kk < 4; ++kk) {
                int krow = k4 * 4 + kk;        // (krow>>2)&7 == k4&7
                float4 vv = *(const float4*)&Vs[krow * 64 + ((tx ^ (k4 & 7)) << 2)];
                #pragma unroll
                for (int i = 0; i < 4; ++i) {
                    o[i][0] += pa[i][kk] * vv.x;
                    o[i][1] += pa[i][kk] * vv.y;
                    o[i][2] += pa[i][kk] * vv.z;
                    o[i][3] += pa[i][kk] * vv.w;
                }
            }
        }
        __syncthreads();   // before next iteration's staging overwrites Ks/Vs
    }

    float* obase = out + (size_t)(b * SEQ + q0) * DMODEL + h * HEADD;
    #pragma unroll
    for (int i = 0; i < 4; ++i) {
        float inv = 1.0f / l[i];
        float4 ov = make_float4(o[i][0] * inv, o[i][1] * inv, o[i][2] * inv, o[i][3] * inv);
        *(float4*)(obase + (size_t)(ty * 4 + i) * DMODEL + (tx << 2)) = ov;
    }
}

// ---------------------------------------------------------------------------
// Host launcher
// ---------------------------------------------------------------------------
static inline size_t align_up(size_t x, size_t a) { return (x + a - 1) & ~(a - 1); }

extern "C" void kernel_launch(void* const* d_in, const int* in_sizes, int n_in,
                              void* d_out, int out_size, void* d_ws, size_t ws_size,
                              hipStream_t stream) {
    const int*   input_ids = (const int*)d_in[0];
    const float* amask     = (const float*)d_in[1];
    const float* tok_emb   = (const float*)d_in[2];
    const float* pos_emb   = (const float*)d_in[3];
    const float* ln1_g = (const float*)d_in[4];
    const float* ln1_b = (const float*)d_in[5];
    const float* Wq = (const float*)d_in[6];
    const float* bq = (const float*)d_in[7];
    const float* Wk = (const float*)d_in[8];
    const float* bk = (const float*)d_in[9];
    const float* Wv = (const float*)d_in[10];
    const float* bv = (const float*)d_in[11];
    const float* Wp = (const float*)d_in[12];
    const float* bp = (const float*)d_in[13];
    const float* ln2_g = (const float*)d_in[14];
    const float* ln2_b = (const float*)d_in[15];
    const float* W1 = (const float*)d_in[16];
    const float* b1 = (const float*)d_in[17];
    const float* W2 = (const float*)d_in[18];
    const float* b2 = (const float*)d_in[19];
    const float* lnf_g = (const float*)d_in[20];
    const float* lnf_b = (const float*)d_in[21];

    float* logits = (float*)d_out;

    // Workspace carve-out
    char* ws = (char*)d_ws;
    size_t off = 0;
    auto carve = [&](size_t nbytes) -> char* {
        char* p = ws + off;
        off = align_up(off + nbytes, 256);
        return p;
    };
    int*   pos_ids = (int*)  carve((size_t)MROWS * sizeof(int));
    float* x    = (float*)carve((size_t)MROWS * DMODEL * sizeof(float));
    float* h    = (float*)carve((size_t)MROWS * DMODEL * sizeof(float));
    float* qb   = (float*)carve((size_t)MROWS * DMODEL * sizeof(float));
    float* kb   = (float*)carve((size_t)MROWS * DMODEL * sizeof(float));
    float* vb   = (float*)carve((size_t)MROWS * DMODEL * sizeof(float));
    float* attn = (float*)carve((size_t)MROWS * DMODEL * sizeof(float));
    float* ff   = (float*)carve((size_t)MROWS * DFF    * sizeof(float));
    (void)ws_size; (void)in_sizes; (void)n_in; (void)out_size;

    // 1. position ids + embedding
    pos_ids_kernel<<<(MROWS + 255) / 256, 256, 0, stream>>>(amask, pos_ids);
    embed_kernel<<<(MROWS * DMODEL + 255) / 256, 256, 0, stream>>>(
        input_ids, pos_ids, tok_emb, pos_emb, x);

    dim3 gD((DMODEL + BN - 1) / BN, (MROWS + BM - 1) / BM);     // 12 x 32
    dim3 gF((DFF    + BN - 1) / BN, (MROWS + BM - 1) / BM);     // 48 x 32
    dim3 gV((VOCAB  + BN - 1) / BN, (MROWS + BM - 1) / BM);     // 786 x 32

    for (int l = 0; l < NLAYER; ++l) {
        const size_t oD  = (size_t)l * DMODEL;
        const size_t oDD = (size_t)l * DMODEL * DMODEL;
        const size_t oDF = (size_t)l * DMODEL * DFF;

        // h = LN1(x)
        layernorm_kernel<<<MROWS, 256, 0, stream>>>(x, ln1_g + oD, ln1_b + oD, h);
        // q,k,v = h @ W + b
        gemm_kernel<0, 0><<<gD, 256, 0, stream>>>(h, Wq + oDD, bq + oD, nullptr, qb,
                                                  MROWS, DMODEL, DMODEL);
        gemm_kernel<0, 0><<<gD, 256, 0, stream>>>(h, Wk + oDD, bk + oD, nullptr, kb,
                                                  MROWS, DMODEL, DMODEL);
        gemm_kernel<0, 0><<<gD, 256, 0, stream>>>(h, Wv + oDD, bv + oD, nullptr, vb,
                                                  MROWS, DMODEL, DMODEL);
        // attn = softmax(qk^T * scale + mask) @ v  — tiled flash attention
        flash_attn_kernel<<<BATCH * NHEAD * (SEQ / 64), 256, 0, stream>>>(
            qb, kb, vb, amask, attn);
        // x = x + attn @ Wp + bp
        gemm_kernel<0, 0><<<gD, 256, 0, stream>>>(attn, Wp + oDD, bp + oD, x, x,
                                                  MROWS, DMODEL, DMODEL);
        // h = LN2(x)
        layernorm_kernel<<<MROWS, 256, 0, stream>>>(x, ln2_g + oD, ln2_b + oD, h);
        // ff = gelu(h @ W1 + b1)
        gemm_kernel<0, 1><<<gF, 256, 0, stream>>>(h, W1 + oDF, b1 + (size_t)l * DFF, nullptr, ff,
                                                  MROWS, DFF, DMODEL);
        // x = x + ff @ W2 + b2
        gemm_kernel<0, 0><<<gD, 256, 0, stream>>>(ff, W2 + oDF, b2 + oD, x, x,
                                                  MROWS, DMODEL, DFF);
    }

    // final LN + tied LM head: logits = h @ tok_emb^T
    layernorm_kernel<<<MROWS, 256, 0, stream>>>(x, lnf_g, lnf_b, h);
    gemm_kernel<1, 0><<<gV, 256, 0, stream>>>(h, tok_emb, nullptr, nullptr, logits,
                                              MROWS, VOCAB, DMODEL);
}

// Round 2
// 7064.953 us; speedup vs baseline: 3.5439x; 1.8061x over previous
//
#include <hip/hip_runtime.h>
#include <math.h>

// Problem constants (GPT-2 small, B=2, S=1024)
#define VOCAB 50257
#define DMODEL 768
#define NHEAD 12
#define NPOS 1024
#define NLAYER 12
#define BATCH 2
#define SEQ 1024
#define HEADD 64
#define DFF 3072
#define MROWS (BATCH * SEQ)   // 2048
#define DQKV 2304             // fused q|k|v row width

typedef __attribute__((ext_vector_type(8))) short bf16x8;
typedef __attribute__((ext_vector_type(4))) float f32x4;

// split fp32 into hi+lo bf16 (RNE both); x ~= hi + lo with ~2^-18 rel error
__device__ inline void split_bf16(float x, ushort& hi, ushort& lo) {
    unsigned u = __float_as_uint(x);
    unsigned hu = (u + 0x7FFFu + ((u >> 16) & 1u)) & 0xFFFF0000u;
    float hf = __uint_as_float(hu);
    hi = (ushort)(hu >> 16);
    float r = x - hf;
    unsigned ru = __float_as_uint(r);
    lo = (ushort)((ru + 0x7FFFu + ((ru >> 16) & 1u)) >> 16);
}

// ---------------------------------------------------------------------------
// pos_ids: cumsum(mask)-1, pinned to 0 where mask==0
// ---------------------------------------------------------------------------
__global__ void pos_ids_kernel(const float* __restrict__ mask, int* __restrict__ pos_ids) {
    int tid = blockIdx.x * blockDim.x + threadIdx.x;
    if (tid >= BATCH * SEQ) return;
    int b = tid / SEQ;
    int s = tid % SEQ;
    float am = mask[tid];
    if (am == 0.0f) { pos_ids[tid] = 0; return; }
    float acc = 0.0f;
    const float* row = mask + b * SEQ;
    for (int t = 0; t <= s; ++t) acc += row[t];
    pos_ids[tid] = (int)(acc - 1.0f);
}

// ---------------------------------------------------------------------------
// embedding: x[bs, d] = tok_emb[ids[bs]][d] + pos_emb[pos_ids[bs]][d]
// ---------------------------------------------------------------------------
__global__ void embed_kernel(const int* __restrict__ ids, const int* __restrict__ pos_ids,
                             const float* __restrict__ tok_emb, const float* __restrict__ pos_emb,
                             float* __restrict__ x) {
    int idx = blockIdx.x * blockDim.x + threadIdx.x;
    if (idx >= MROWS * DMODEL) return;
    int bs = idx / DMODEL;
    int d  = idx % DMODEL;
    int id = ids[bs];
    int p  = pos_ids[bs];
    x[idx] = tok_emb[(size_t)id * DMODEL + d] + pos_emb[(size_t)p * DMODEL + d];
}

// ---------------------------------------------------------------------------
// LayerNorm: one block (256 threads) per row of 768, emits hi/lo bf16 split
// (LN outputs feed only MFMA GEMMs, so no fp32 copy needed)
// ---------------------------------------------------------------------------
__device__ inline float wave_sum64(float v) {
    #pragma unroll
    for (int off = 32; off >= 1; off >>= 1) v += __shfl_xor(v, off, 64);
    return v;
}

__global__ __launch_bounds__(256) void layernorm_kernel(
    const float* __restrict__ x, const float* __restrict__ g, const float* __restrict__ b,
    ushort* __restrict__ ohi, ushort* __restrict__ olo) {
    int row = blockIdx.x;
    int tid = threadIdx.x;
    const float* xr = x + (size_t)row * DMODEL;
    float v0 = xr[tid], v1 = xr[tid + 256], v2 = xr[tid + 512];

    __shared__ float red[4];
    int wave = tid >> 6, lane = tid & 63;

    float s = wave_sum64(v0 + v1 + v2);
    if (lane == 0) red[wave] = s;
    __syncthreads();
    float mean = (red[0] + red[1] + red[2] + red[3]) * (1.0f / DMODEL);
    __syncthreads();

    float d0 = v0 - mean, d1 = v1 - mean, d2 = v2 - mean;
    float s2 = wave_sum64(d0 * d0 + d1 * d1 + d2 * d2);
    if (lane == 0) red[wave] = s2;
    __syncthreads();
    float var = (red[0] + red[1] + red[2] + red[3]) * (1.0f / DMODEL);
    float inv = 1.0f / sqrtf(var + 1e-5f);

    size_t o = (size_t)row * DMODEL;
    float y0 = d0 * inv * g[tid]       + b[tid];
    float y1 = d1 * inv * g[tid + 256] + b[tid + 256];
    float y2 = d2 * inv * g[tid + 512] + b[tid + 512];
    ushort h_, l_;
    split_bf16(y0, h_, l_); ohi[o + tid]       = h_; olo[o + tid]       = l_;
    split_bf16(y1, h_, l_); ohi[o + tid + 256] = h_; olo[o + tid + 256] = l_;
    split_bf16(y2, h_, l_); ohi[o + tid + 512] = h_; olo[o + tid + 512] = l_;
}

// ---------------------------------------------------------------------------
// Weight transpose + split: in W (Kd, Nd) fp32 row-major (one layer slice,
// selected by blockIdx.z among up to 3 source tensors for QKV fusion) ->
// out hi/lo bf16 (N, K) row-major at row offset blockIdx.z * Nd.
// ---------------------------------------------------------------------------
__global__ __launch_bounds__(256) void wsplit_kernel(
    const float* __restrict__ Wa, const float* __restrict__ Wb, const float* __restrict__ Wc,
    ushort* __restrict__ hi, ushort* __restrict__ lo, int Kd, int Nd) {
    __shared__ float T[32][33];
    const float* W = (blockIdx.z == 0) ? Wa : (blockIdx.z == 1 ? Wb : Wc);
    int nOff = blockIdx.z * Nd;
    int n0 = blockIdx.x << 5, k0 = blockIdx.y << 5;
    int t = threadIdx.x;
    int lr = t >> 3, lc = (t & 7) << 2;
    float4 v = *(const float4*)(W + (size_t)(k0 + lr) * Nd + n0 + lc);
    T[lr][lc] = v.x; T[lr][lc + 1] = v.y; T[lr][lc + 2] = v.z; T[lr][lc + 3] = v.w;
    __syncthreads();
    // write transposed: n-row = n0+lr, k columns k0+lc..+3
    ushort h4[4], l4[4];
    #pragma unroll
    for (int j = 0; j < 4; ++j) split_bf16(T[lc + j][lr], h4[j], l4[j]);
    size_t o = (size_t)(nOff + n0 + lr) * Kd + k0 + lc;
    *(ushort4*)&hi[o] = make_ushort4(h4[0], h4[1], h4[2], h4[3]);
    *(ushort4*)&lo[o] = make_ushort4(l4[0], l4[1], l4[2], l4[3]);
}

// concat per-layer q,k,v biases into (L, 2304)
__global__ void bias_concat_kernel(const float* __restrict__ bq, const float* __restrict__ bk,
                                   const float* __restrict__ bv, float* __restrict__ out) {
    int t = blockIdx.x * blockDim.x + threadIdx.x;
    if (t >= NLAYER * DQKV) return;
    int l = t / DQKV, c = t % DQKV;
    float v = (c < 768) ? bq[l * 768 + c]
            : (c < 1536) ? bk[l * 768 + c - 768]
                         : bv[l * 768 + c - 1536];
    out[t] = v;
}

// ---------------------------------------------------------------------------
// Split-bf16 MFMA GEMM: C[M,N] = (Ahi+Alo)[M,K] @ (Bhi+Blo)[N,K]^T (3 products)
// 128x128x32 tile, 256 threads = 4 waves (2x2), 4x4 16x16 fragments per wave.
// LDS row stride 40 ushorts (80B) -> fragment ds_read_b128 lands 2-way bank
// aliasing (free). B stored (N,K) so 8 consecutive k per lane are contiguous.
// EPI: 0 = +bias, fp32 C; 1 = +bias +Res, fp32 C; 2 = +bias +GELU -> hi/lo;
//      3 = no bias, fp32 C (LM head).
// BF32: B streamed from fp32 (N,K) with row guard, split inline (LM head).
// ---------------------------------------------------------------------------
#define GBM 128
#define GBN 128
#define GBK 32
#define LDK 40

template<int EPI, int BF32>
__global__ __launch_bounds__(256) void mfma_gemm(
    const ushort* __restrict__ Ahi, const ushort* __restrict__ Alo,
    const ushort* __restrict__ Bhi, const ushort* __restrict__ Blo,
    const float*  __restrict__ Bf32, int Brows,
    const float*  __restrict__ bias, const float* __restrict__ Res,
    float* __restrict__ C, ushort* __restrict__ Chi, ushort* __restrict__ Clo,
    int M, int N, int K) {
    __shared__ __align__(16) ushort As_hi[GBM * LDK];
    __shared__ __align__(16) ushort As_lo[GBM * LDK];
    __shared__ __align__(16) ushort Bs_hi[GBN * LDK];
    __shared__ __align__(16) ushort Bs_lo[GBN * LDK];

    const int tid = threadIdx.x;
    const int m0 = blockIdx.x * GBM;   // grid.x = M/128 (fast dim: blocks sharing a B strip go together)
    const int n0 = blockIdx.y * GBN;
    const int lane = tid & 63;
    const int wid  = tid >> 6;
    const int wm = (wid >> 1) << 6;
    const int wn = (wid & 1) << 6;
    const int lr = lane & 15;          // A row / B col / D col within fragment
    const int lk = lane >> 4;          // k-group; D row group

    // staging: thread covers 16 elements (one half-row of a 128x32 tile)
    const int sr  = tid >> 1;
    const int sko = (tid & 1) << 4;

    const ushort* Ah = Ahi + (size_t)(m0 + sr) * K + sko;
    const ushort* Al = Alo + (size_t)(m0 + sr) * K + sko;
    ushort* ash = &As_hi[sr * LDK + sko];
    ushort* asl = &As_lo[sr * LDK + sko];
    ushort* bsh = &Bs_hi[sr * LDK + sko];
    ushort* bsl = &Bs_lo[sr * LDK + sko];

    const ushort* Bh = nullptr; const ushort* Bl = nullptr;
    const float* Bf = nullptr; bool bok = true;
    if constexpr (BF32) {
        Bf = Bf32 + (size_t)(n0 + sr) * K + sko;
        bok = (n0 + sr) < Brows;
    } else {
        Bh = Bhi + (size_t)(n0 + sr) * K + sko;
        Bl = Blo + (size_t)(n0 + sr) * K + sko;
    }

    f32x4 acc[4][4];
    const f32x4 zero = {0.f, 0.f, 0.f, 0.f};
    #pragma unroll
    for (int i = 0; i < 4; ++i)
        #pragma unroll
        for (int j = 0; j < 4; ++j) acc[i][j] = zero;

    for (int k0 = 0; k0 < K; k0 += GBK) {
        *(float4*)ash       = *(const float4*)(Ah + k0);
        *(float4*)(ash + 8) = *(const float4*)(Ah + k0 + 8);
        *(float4*)asl       = *(const float4*)(Al + k0);
        *(float4*)(asl + 8) = *(const float4*)(Al + k0 + 8);
        if constexpr (!BF32) {
            *(float4*)bsh       = *(const float4*)(Bh + k0);
            *(float4*)(bsh + 8) = *(const float4*)(Bh + k0 + 8);
            *(float4*)bsl       = *(const float4*)(Bl + k0);
            *(float4*)(bsl + 8) = *(const float4*)(Bl + k0 + 8);
        } else {
            float fv[16];
            #pragma unroll
            for (int c = 0; c < 4; ++c) {
                float4 t = bok ? *(const float4*)(Bf + k0 + c * 4)
                               : make_float4(0.f, 0.f, 0.f, 0.f);
                fv[c * 4 + 0] = t.x; fv[c * 4 + 1] = t.y;
                fv[c * 4 + 2] = t.z; fv[c * 4 + 3] = t.w;
            }
            ushort hh[16], ll[16];
            #pragma unroll
            for (int e = 0; e < 16; ++e) split_bf16(fv[e], hh[e], ll[e]);
            #pragma unroll
            for (int c = 0; c < 2; ++c) {
                uint4 ph, pl;
                ph.x = (uint)hh[c*8+0] | ((uint)hh[c*8+1] << 16);
                ph.y = (uint)hh[c*8+2] | ((uint)hh[c*8+3] << 16);
                ph.z = (uint)hh[c*8+4] | ((uint)hh[c*8+5] << 16);
                ph.w = (uint)hh[c*8+6] | ((uint)hh[c*8+7] << 16);
                pl.x = (uint)ll[c*8+0] | ((uint)ll[c*8+1] << 16);
                pl.y = (uint)ll[c*8+2] | ((uint)ll[c*8+3] << 16);
                pl.z = (uint)ll[c*8+4] | ((uint)ll[c*8+5] << 16);
                pl.w = (uint)ll[c*8+6] | ((uint)ll[c*8+7] << 16);
                *(uint4*)(bsh + c * 8) = ph;
                *(uint4*)(bsl + c * 8) = pl;
            }
        }
        __syncthreads();

        const ushort* aph = &As_hi[(wm + lr) * LDK + (lk << 3)];
        const ushort* apl = &As_lo[(wm + lr) * LDK + (lk << 3)];
        const ushort* bph = &Bs_hi[(wn + lr) * LDK + (lk << 3)];
        const ushort* bpl = &Bs_lo[(wn + lr) * LDK + (lk << 3)];
        bf16x8 afh[4], afl[4], bfh[4], bfl[4];
        #pragma unroll
        for (int i = 0; i < 4; ++i) {
            afh[i] = *(const bf16x8*)(aph + i * 16 * LDK);
            afl[i] = *(const bf16x8*)(apl + i * 16 * LDK);
            bfh[i] = *(const bf16x8*)(bph + i * 16 * LDK);
            bfl[i] = *(const bf16x8*)(bpl + i * 16 * LDK);
        }
        #pragma unroll
        for (int i = 0; i < 4; ++i)
            #pragma unroll
            for (int j = 0; j < 4; ++j) {
                acc[i][j] = __builtin_amdgcn_mfma_f32_16x16x32_bf16(afh[i], bfh[j], acc[i][j], 0, 0, 0);
                acc[i][j] = __builtin_amdgcn_mfma_f32_16x16x32_bf16(afh[i], bfl[j], acc[i][j], 0, 0, 0);
                acc[i][j] = __builtin_amdgcn_mfma_f32_16x16x32_bf16(afl[i], bfh[j], acc[i][j], 0, 0, 0);
            }
        __syncthreads();
    }

    // epilogue: D[row][col], col = lane&15, row = (lane>>4)*4 + reg  [verified layout]
    #pragma unroll
    for (int j = 0; j < 4; ++j) {
        int col = n0 + wn + j * 16 + lr;
        if (col >= N) continue;
        float bv = 0.f;
        if constexpr (EPI != 3) bv = bias[col];
        #pragma unroll
        for (int i = 0; i < 4; ++i) {
            #pragma unroll
            for (int r = 0; r < 4; ++r) {
                int row = m0 + wm + i * 16 + (lk << 2) + r;
                float vv = acc[i][j][r] + bv;
                size_t idx = (size_t)row * N + col;
                if constexpr (EPI == 2) {
                    vv = vv * 0.5f * (1.0f + erff(vv * 0.70710678118654752f));
                    ushort h_, l_; split_bf16(vv, h_, l_);
                    Chi[idx] = h_; Clo[idx] = l_;
                } else if constexpr (EPI == 1) {
                    C[idx] = vv + Res[idx];
                } else {
                    C[idx] = vv;
                }
            }
        }
    }
}

// ---------------------------------------------------------------------------
// Flash attention, tiled. One 256-thread block per (b, h, 64-row q-tile).
// q,k,v rows have stride DQKV (fused qkv buffer); out is hi/lo bf16 split
// with row stride DMODEL (feeds the proj MFMA GEMM directly).
// ---------------------------------------------------------------------------
__global__ __launch_bounds__(256) void flash_attn_kernel(
    const float* __restrict__ q, const float* __restrict__ k, const float* __restrict__ v,
    const float* __restrict__ amask, ushort* __restrict__ ohi, ushort* __restrict__ olo) {
    __shared__ __align__(16) float Qs[64 * 64];
    __shared__ __align__(16) float Ks[64 * 64];   // reused as P after S-compute
    __shared__ __align__(16) float Vs[64 * 64];

    const int nqt = SEQ / 64;
    int qt = blockIdx.x % nqt;
    int h  = (blockIdx.x / nqt) % NHEAD;
    int b  = blockIdx.x / (nqt * NHEAD);
    int q0 = qt * 64;

    int tid = threadIdx.x;
    int tx = tid & 15, ty = tid >> 4;

    const float* qbase = q + (size_t)(b * SEQ + q0) * DQKV + h * HEADD;
    const float* kbase = k + (size_t)(b * SEQ) * DQKV + h * HEADD;
    const float* vbase = v + (size_t)(b * SEQ) * DQKV + h * HEADD;
    const float* mrow  = amask + (size_t)b * SEQ;

    // stage Q (pre-scaled by 1/sqrt(64))
    #pragma unroll
    for (int i = 0; i < 4; ++i) {
        int idx = tid + i * 256;
        int r = idx >> 4, c4 = idx & 15;
        float4 val = *(const float4*)(qbase + (size_t)r * DQKV + (c4 << 2));
        val.x *= 0.125f; val.y *= 0.125f; val.z *= 0.125f; val.w *= 0.125f;
        int s4 = c4 ^ ((r >> 2) & 7);
        *(float4*)&Qs[r * 64 + (s4 << 2)] = val;
    }

    float m[4], l[4], o[4][4];
    #pragma unroll
    for (int i = 0; i < 4; ++i) {
        m[i] = -3.402823466e38f; l[i] = 0.0f;
        #pragma unroll
        for (int j = 0; j < 4; ++j) o[i][j] = 0.0f;
    }

    for (int j0 = 0; j0 <= q0; j0 += 64) {
        #pragma unroll
        for (int i = 0; i < 4; ++i) {
            int idx = tid + i * 256;
            int r = idx >> 4, c4 = idx & 15;
            int s4 = c4 ^ ((r >> 2) & 7);
            *(float4*)&Ks[r * 64 + (s4 << 2)] =
                *(const float4*)(kbase + (size_t)(j0 + r) * DQKV + (c4 << 2));
            *(float4*)&Vs[r * 64 + (s4 << 2)] =
                *(const float4*)(vbase + (size_t)(j0 + r) * DQKV + (c4 << 2));
        }
        __syncthreads();

        float s[4][4] = {};
        #pragma unroll
        for (int d4 = 0; d4 < 16; ++d4) {
            float4 qv[4], kv[4];
            #pragma unroll
            for (int i = 0; i < 4; ++i)
                qv[i] = *(const float4*)&Qs[(ty * 4 + i) * 64 + ((d4 ^ (ty & 7)) << 2)];
            #pragma unroll
            for (int j = 0; j < 4; ++j)
                kv[j] = *(const float4*)&Ks[(tx * 4 + j) * 64 + ((d4 ^ (tx & 7)) << 2)];
            #pragma unroll
            for (int i = 0; i < 4; ++i)
                #pragma unroll
                for (int j = 0; j < 4; ++j)
                    s[i][j] += qv[i].x * kv[j].x + qv[i].y * kv[j].y
                             + qv[i].z * kv[j].z + qv[i].w * kv[j].w;
        }

        #pragma unroll
        for (int j = 0; j < 4; ++j) {
            int kc = j0 + tx * 4 + j;
            float am = mrow[kc];
            #pragma unroll
            for (int i = 0; i < 4; ++i) {
                int qr = q0 + ty * 4 + i;
                if (kc > qr || am == 0.0f) s[i][j] = -3.402823466e38f;
            }
        }

        float p[4][4];
        #pragma unroll
        for (int i = 0; i < 4; ++i) {
            float mx = fmaxf(fmaxf(s[i][0], s[i][1]), fmaxf(s[i][2], s[i][3]));
            #pragma unroll
            for (int off = 1; off < 16; off <<= 1) mx = fmaxf(mx, __shfl_xor(mx, off, 16));
            float mn = fmaxf(m[i], mx);
            float alpha = expf(m[i] - mn);
            float sum = 0.0f;
            #pragma unroll
            for (int j = 0; j < 4; ++j) { p[i][j] = expf(s[i][j] - mn); sum += p[i][j]; }
            #pragma unroll
            for (int off = 1; off < 16; off <<= 1) sum += __shfl_xor(sum, off, 16);
            l[i] = l[i] * alpha + sum;
            m[i] = mn;
            #pragma unroll
            for (int j = 0; j < 4; ++j) o[i][j] *= alpha;
        }

        __syncthreads();

        #pragma unroll
        for (int i = 0; i < 4; ++i) {
            float4 pv = make_float4(p[i][0], p[i][1], p[i][2], p[i][3]);
            *(float4*)&Ks[(ty * 4 + i) * 64 + ((tx ^ (ty & 7)) << 2)] = pv;
        }
        __syncthreads();

        #pragma unroll
        for (int k4 = 0; k4 < 16; ++k4) {
            float pa[4][4];
            #pragma unroll
            for (int i = 0; i < 4; ++i) {
                float4 t = *(const float4*)&Ks[(ty * 4 + i) * 64 + ((k4 ^ (ty & 7)) << 2)];
                pa[i][0] = t.x; pa[i][1] = t.y; pa[i][2] = t.z; pa[i][3] = t.w;
            }
            #pragma unroll
            for (int kk = 0; kk < 4; ++kk) {
                int krow = k4 * 4 + kk;
                float4 vv = *(const float4*)&Vs[krow * 64 + ((tx ^ (k4 & 7)) << 2)];
                #pragma unroll
                for (int i = 0; i < 4; ++i) {
                    o[i][0] += pa[i][kk] * vv.x;
                    o[i][1] += pa[i][kk] * vv.y;
                    o[i][2] += pa[i][kk] * vv.z;
                    o[i][3] += pa[i][kk] * vv.w;
                }
            }
        }
        __syncthreads();
    }

    #pragma unroll
    for (int i = 0; i < 4; ++i) {
        float inv = 1.0f / l[i];
        ushort h4[4], l4[4];
        #pragma unroll
        for (int j = 0; j < 4; ++j) split_bf16(o[i][j] * inv, h4[j], l4[j]);
        size_t ob = (size_t)(b * SEQ + q0 + ty * 4 + i) * DMODEL + h * HEADD + tx * 4;
        *(ushort4*)&ohi[ob] = make_ushort4(h4[0], h4[1], h4[2], h4[3]);
        *(ushort4*)&olo[ob] = make_ushort4(l4[0], l4[1], l4[2], l4[3]);
    }
}

// ---------------------------------------------------------------------------
// Host launcher
// ---------------------------------------------------------------------------
static inline size_t align_up(size_t x, size_t a) { return (x + a - 1) & ~(a - 1); }

extern "C" void kernel_launch(void* const* d_in, const int* in_sizes, int n_in,
                              void* d_out, int out_size, void* d_ws, size_t ws_size,
                              hipStream_t stream) {
    const int*   input_ids = (const int*)d_in[0];
    const float* amask     = (const float*)d_in[1];
    const float* tok_emb   = (const float*)d_in[2];
    const float* pos_emb   = (const float*)d_in[3];
    const float* ln1_g = (const float*)d_in[4];
    const float* ln1_b = (const float*)d_in[5];
    const float* Wq = (const float*)d_in[6];
    const float* bq = (const float*)d_in[7];
    const float* Wk = (const float*)d_in[8];
    const float* bk = (const float*)d_in[9];
    const float* Wv = (const float*)d_in[10];
    const float* bv = (const float*)d_in[11];
    const float* Wp = (const float*)d_in[12];
    const float* bp = (const float*)d_in[13];
    const float* ln2_g = (const float*)d_in[14];
    const float* ln2_b = (const float*)d_in[15];
    const float* W1 = (const float*)d_in[16];
    const float* b1 = (const float*)d_in[17];
    const float* W2 = (const float*)d_in[18];
    const float* b2 = (const float*)d_in[19];
    const float* lnf_g = (const float*)d_in[20];
    const float* lnf_b = (const float*)d_in[21];

    float* logits = (float*)d_out;

    char* ws = (char*)d_ws;
    size_t off = 0;
    auto carve = [&](size_t nbytes) -> char* {
        char* p = ws + off;
        off = align_up(off + nbytes, 256);
        return p;
    };
    int*    pos_ids = (int*)   carve((size_t)MROWS * sizeof(int));
    float*  x       = (float*) carve((size_t)MROWS * DMODEL * sizeof(float));
    float*  qkv     = (float*) carve((size_t)MROWS * DQKV * sizeof(float));
    ushort* attn_hi = (ushort*)carve((size_t)MROWS * DMODEL * 2);
    ushort* attn_lo = (ushort*)carve((size_t)MROWS * DMODEL * 2);
    ushort* h_hi    = (ushort*)carve((size_t)MROWS * DMODEL * 2);
    ushort* h_lo    = (ushort*)carve((size_t)MROWS * DMODEL * 2);
    ushort* ff_hi   = (ushort*)carve((size_t)MROWS * DFF * 2);
    ushort* ff_lo   = (ushort*)carve((size_t)MROWS * DFF * 2);
    ushort* wqkv_hi = (ushort*)carve((size_t)DQKV * DMODEL * 2);
    ushort* wqkv_lo = (ushort*)carve((size_t)DQKV * DMODEL * 2);
    ushort* wp_hi   = (ushort*)carve((size_t)DMODEL * DMODEL * 2);
    ushort* wp_lo   = (ushort*)carve((size_t)DMODEL * DMODEL * 2);
    ushort* w1_hi   = (ushort*)carve((size_t)DFF * DMODEL * 2);
    ushort* w1_lo   = (ushort*)carve((size_t)DFF * DMODEL * 2);
    ushort* w2_hi   = (ushort*)carve((size_t)DMODEL * DFF * 2);
    ushort* w2_lo   = (ushort*)carve((size_t)DMODEL * DFF * 2);
    float*  bqkv    = (float*) carve((size_t)NLAYER * DQKV * sizeof(float));
    (void)ws_size; (void)in_sizes; (void)n_in; (void)out_size;

    pos_ids_kernel<<<(MROWS + 255) / 256, 256, 0, stream>>>(amask, pos_ids);
    embed_kernel<<<(MROWS * DMODEL + 255) / 256, 256, 0, stream>>>(
        input_ids, pos_ids, tok_emb, pos_emb, x);
    bias_concat_kernel<<<(NLAYER * DQKV + 255) / 256, 256, 0, stream>>>(bq, bk, bv, bqkv);

    const int MT = MROWS / GBM;   // 16

    for (int l = 0; l < NLAYER; ++l) {
        const size_t oD  = (size_t)l * DMODEL;
        const size_t oDD = (size_t)l * DMODEL * DMODEL;
        const size_t oDF = (size_t)l * DMODEL * DFF;

        // per-layer weight transpose+split into reused slabs
        wsplit_kernel<<<dim3(24, 24, 3), 256, 0, stream>>>(
            Wq + oDD, Wk + oDD, Wv + oDD, wqkv_hi, wqkv_lo, DMODEL, DMODEL);
        wsplit_kernel<<<dim3(24, 24, 1), 256, 0, stream>>>(
            Wp + oDD, Wp + oDD, Wp + oDD, wp_hi, wp_lo, DMODEL, DMODEL);
        wsplit_kernel<<<dim3(96, 24, 1), 256, 0, stream>>>(
            W1 + oDF, W1 + oDF, W1 + oDF, w1_hi, w1_lo, DMODEL, DFF);
        wsplit_kernel<<<dim3(24, 96, 1), 256, 0, stream>>>(
            W2 + oDF, W2 + oDF, W2 + oDF, w2_hi, w2_lo, DFF, DMODEL);

        // h = LN1(x) -> hi/lo
        layernorm_kernel<<<MROWS, 256, 0, stream>>>(x, ln1_g + oD, ln1_b + oD, h_hi, h_lo);
        // qkv = h @ [Wq|Wk|Wv] + [bq|bk|bv]
        mfma_gemm<0, 0><<<dim3(MT, DQKV / GBN), 256, 0, stream>>>(
            h_hi, h_lo, wqkv_hi, wqkv_lo, nullptr, 0, bqkv + (size_t)l * DQKV,
            nullptr, qkv, nullptr, nullptr, MROWS, DQKV, DMODEL);
        // attn (hi/lo out)
        flash_attn_kernel<<<BATCH * NHEAD * (SEQ / 64), 256, 0, stream>>>(
            qkv, qkv + 768, qkv + 1536, amask, attn_hi, attn_lo);
        // x = x + attn @ Wp + bp
        mfma_gemm<1, 0><<<dim3(MT, DMODEL / GBN), 256, 0, stream>>>(
            attn_hi, attn_lo, wp_hi, wp_lo, nullptr, 0, bp + oD,
            x, x, nullptr, nullptr, MROWS, DMODEL, DMODEL);
        // h = LN2(x) -> hi/lo
        layernorm_kernel<<<MROWS, 256, 0, stream>>>(x, ln2_g + oD, ln2_b + oD, h_hi, h_lo);
        // ff = gelu(h @ W1 + b1) -> hi/lo
        mfma_gemm<2, 0><<<dim3(MT, DFF / GBN), 256, 0, stream>>>(
            h_hi, h_lo, w1_hi, w1_lo, nullptr, 0, b1 + (size_t)l * DFF,
            nullptr, nullptr, ff_hi, ff_lo, MROWS, DFF, DMODEL);
        // x = x + ff @ W2 + b2
        mfma_gemm<1, 0><<<dim3(MT, DMODEL / GBN), 256, 0, stream>>>(
            ff_hi, ff_lo, w2_hi, w2_lo, nullptr, 0, b2 + oD,
            x, x, nullptr, nullptr, MROWS, DMODEL, DFF);
    }

    // final LN + tied LM head (B = tok_emb fp32 (V,768), split inline)
    layernorm_kernel<<<MROWS, 256, 0, stream>>>(x, lnf_g, lnf_b, h_hi, h_lo);
    mfma_gemm<3, 1><<<dim3(MT, (VOCAB + GBN - 1) / GBN), 256, 0, stream>>>(
        h_hi, h_lo, nullptr, nullptr, tok_emb, VOCAB, nullptr,
        nullptr, logits, nullptr, nullptr, MROWS, VOCAB, DMODEL);
}